// Round 1
// baseline (334.498 us; speedup 1.0000x reference)
//
#include <hip/hip_runtime.h>
#include <hip/hip_bf16.h>
#include <cstdint>
#include <cstddef>

// Problem constants (fixed by reference)
#define BROWS   16384
#define LDIM    128
#define HDIM    512
#define KDIM    1152            // LABEL_DIM + 2*H_DIM
#define NGATES  2560            // 5 * HDIM  (i, o, u, f0, f1)

// workspace layout (bytes)
#define XB_BYTES  ((size_t)BROWS * KDIM * 2)            // 37,748,736
#define WB_BYTES  ((size_t)NGATES * KDIM * 2)           //  5,898,240
// gates: BROWS * NGATES bf16 = 83,886,080

using f32x4  = __attribute__((ext_vector_type(4))) float;
using bfrag  = __attribute__((ext_vector_type(8))) short;   // 8 bf16 = 4 VGPRs
using short4v = __attribute__((ext_vector_type(4))) short;

__device__ __forceinline__ short f2bf(float f) {
    union { float f; uint32_t u; } a; a.f = f;
    uint32_t u = a.u;
    uint32_t lsb = (u >> 16) & 1u;
    u += 0x7fffu + lsb;               // round-to-nearest-even
    return (short)(u >> 16);
}
__device__ __forceinline__ float bf2f(short s) {
    union { uint32_t u; float f; } a;
    a.u = ((uint32_t)(uint16_t)s) << 16;
    return a.f;
}

__device__ __forceinline__ void load_lds16(const void* g, void* l) {
    __builtin_amdgcn_global_load_lds(
        (const __attribute__((address_space(1))) void*)g,
        (__attribute__((address_space(3))) void*)l, 16, 0, 0);
}

// ---------------------------------------------------------------------------
// pack_x: xb[b, 0:128] = label[b,:]; xb[b, 128 + k*512 + j] = children_h[k,b,j]
// one thread per 4 elements (float4 load, 4x bf16 store)
// ---------------------------------------------------------------------------
__global__ __launch_bounds__(256) void pack_x(const float* __restrict__ label,
                                              const float* __restrict__ chh,
                                              short* __restrict__ xb) {
    const int perRow = KDIM / 4;  // 288
    int tid = blockIdx.x * 256 + threadIdx.x;
    int b  = tid / perRow;
    int d4 = (tid - b * perRow) * 4;
    if (b >= BROWS) return;
    float4 v;
    if (d4 < LDIM) {
        v = *(const float4*)(label + (size_t)b * LDIM + d4);
    } else {
        int dd = d4 - LDIM;
        int k  = dd >> 9;           // child index
        int j  = dd & 511;
        v = *(const float4*)(chh + ((size_t)k * BROWS + b) * HDIM + j);
    }
    short4v s;
    s.x = f2bf(v.x); s.y = f2bf(v.y); s.z = f2bf(v.z); s.w = f2bf(v.w);
    *(short4v*)(xb + (size_t)b * KDIM + d4) = s;
}

// ---------------------------------------------------------------------------
// pack_w: Wb row n (0..2559), K-contiguous bf16.
//   g = n>>9: 0->W_i, 1->W_o, 2->W_u, 3->Wf0, 4->Wf1
//   Wf_k row h = [ W_fl[h,:] (128) | W_fs[k,0,h,:] (512) | W_fs[k,1,h,:] (512) ]
// ---------------------------------------------------------------------------
__global__ __launch_bounds__(256) void pack_w(const float* __restrict__ Wi,
                                              const float* __restrict__ Wo,
                                              const float* __restrict__ Wu,
                                              const float* __restrict__ Wfl,
                                              const float* __restrict__ Wfs,
                                              short* __restrict__ Wb) {
    const int perRow = KDIM / 4;  // 288
    int tid = blockIdx.x * 256 + threadIdx.x;
    int n  = tid / perRow;
    int d4 = (tid - n * perRow) * 4;
    if (n >= NGATES) return;
    int g = n >> 9, h = n & 511;
    const float* src;
    if (g == 0)      src = Wi + (size_t)h * KDIM + d4;
    else if (g == 1) src = Wo + (size_t)h * KDIM + d4;
    else if (g == 2) src = Wu + (size_t)h * KDIM + d4;
    else {
        int k = g - 3;
        if (d4 < LDIM) {
            src = Wfl + (size_t)h * LDIM + d4;
        } else {
            int dd = d4 - LDIM;
            int j  = dd >> 9;
            int jj = dd & 511;
            // W_fs[k, j, h, jj]  shape (2,2,512,512)
            src = Wfs + (((size_t)(k * 2 + j) * HDIM + h) * HDIM) + jj;
        }
    }
    float4 v = *(const float4*)src;
    short4v s;
    s.x = f2bf(v.x); s.y = f2bf(v.y); s.z = f2bf(v.z); s.w = f2bf(v.w);
    *(short4v*)(Wb + (size_t)n * KDIM + d4) = s;
}

// ---------------------------------------------------------------------------
// gemm_bt: C[m,n] = sum_k A[m,k] * Bt[n,k]   (A: M x K bf16, Bt: N x K bf16)
// m97 structure: 128x128 tile, BK=32, 256 thr (4 waves, 2x2), 4x4 frags/wave,
// global_load_lds width=16 staging, 16 MFMA / K-step.
// ---------------------------------------------------------------------------
__global__ __launch_bounds__(256) void gemm_bt(const short* __restrict__ A,
                                               const short* __restrict__ Bt,
                                               short* __restrict__ C) {
    __shared__ short As[128 * 32];   // 8 KB
    __shared__ short Bs[128 * 32];   // 8 KB

    const int t    = threadIdx.x;
    const int lane = t & 63;
    const int wave = t >> 6;
    const int wr   = wave >> 1;      // wave row (0..1) -> m offset 64*wr
    const int wc   = wave & 1;       // wave col (0..1) -> n offset 64*wc
    const int quad = lane >> 4;      // 0..3
    const int l16  = lane & 15;

    const int mBase = blockIdx.x * 128;
    const int nBase = blockIdx.y * 128;

    f32x4 acc[4][4] = {};

    // per-thread staging segments: s = t and t+256; row = s>>2, colseg = s&3
    const int s0 = t, s1 = t + 256;
    const int r0 = s0 >> 2, c0 = (s0 & 3) * 8;
    const int r1 = s1 >> 2, c1 = (s1 & 3) * 8;

    const short* Arow0 = A + (size_t)(mBase + r0) * KDIM + c0;
    const short* Arow1 = A + (size_t)(mBase + r1) * KDIM + c1;
    const short* Brow0 = Bt + (size_t)(nBase + r0) * KDIM + c0;
    const short* Brow1 = Bt + (size_t)(nBase + r1) * KDIM + c1;

    for (int k0 = 0; k0 < KDIM; k0 += 32) {
        load_lds16(Arow0 + k0, As + s0 * 8);
        load_lds16(Arow1 + k0, As + s1 * 8);
        load_lds16(Brow0 + k0, Bs + s0 * 8);
        load_lds16(Brow1 + k0, Bs + s1 * 8);
        __syncthreads();   // compiler emits vmcnt(0) drain before s_barrier

        bfrag a[4], b[4];
#pragma unroll
        for (int i = 0; i < 4; ++i) {
            int rowA = wr * 64 + i * 16 + l16;
            a[i] = *(const bfrag*)(As + rowA * 32 + quad * 8);
            int rowB = wc * 64 + i * 16 + l16;
            b[i] = *(const bfrag*)(Bs + rowB * 32 + quad * 8);
        }
#pragma unroll
        for (int i = 0; i < 4; ++i)
#pragma unroll
            for (int j = 0; j < 4; ++j)
                acc[i][j] = __builtin_amdgcn_mfma_f32_16x16x32_bf16(a[i], b[j], acc[i][j], 0, 0, 0);
        __syncthreads();
    }

    // epilogue: D[row = quad*4+r][col = l16] per 16x16 frag; store bf16
#pragma unroll
    for (int i = 0; i < 4; ++i) {
        int m0 = mBase + wr * 64 + i * 16 + quad * 4;
#pragma unroll
        for (int j = 0; j < 4; ++j) {
            int n = nBase + wc * 64 + j * 16 + l16;
#pragma unroll
            for (int r = 0; r < 4; ++r) {
                C[(size_t)(m0 + r) * NGATES + n] = f2bf(acc[i][j][r]);
            }
        }
    }
}

// ---------------------------------------------------------------------------
// epilogue: gates (B x 2560 bf16 logits) -> next_cell, out (fp32)
// ---------------------------------------------------------------------------
__device__ __forceinline__ float fast_sigmoid(float x) {
    return 1.0f / (1.0f + __expf(-x));
}
__device__ __forceinline__ float fast_tanh(float x) {
    float t = __expf(2.0f * x);
    return (t - 1.0f) / (t + 1.0f);
}

__global__ __launch_bounds__(256) void epilogue(const short* __restrict__ gates,
                                                const float* __restrict__ chc,
                                                const float* __restrict__ b_i,
                                                const float* __restrict__ b_o,
                                                const float* __restrict__ b_u,
                                                const float* __restrict__ fbias,
                                                float* __restrict__ out) {
    int idx = blockIdx.x * 256 + threadIdx.x;      // over B*512
    if (idx >= BROWS * HDIM) return;
    int b = idx >> 9;
    int h = idx & 511;
    const short* g = gates + (size_t)b * NGATES;
    float gi  = bf2f(g[h]);
    float go  = bf2f(g[HDIM + h]);
    float gu  = bf2f(g[2 * HDIM + h]);
    float gf0 = bf2f(g[3 * HDIM + h]);
    float gf1 = bf2f(g[4 * HDIM + h]);

    float ig = fast_sigmoid(gi + b_i[h]);
    float og = fast_sigmoid(go + b_o[h]);
    float uu = fast_tanh(gu + b_u[h]);
    float f0 = fast_sigmoid(gf0);
    float f1 = fast_sigmoid(gf1);

    float c0 = chc[idx];
    float c1 = chc[(size_t)BROWS * HDIM + idx];
    float fb = fbias[h];

    float ncell = ig * uu + f0 * c0 + f1 * c1 + fb * (c0 + c1);
    out[idx] = ncell;
    out[(size_t)BROWS * HDIM + idx] = fast_tanh(og * ncell);
}

// ---------------------------------------------------------------------------
extern "C" void kernel_launch(void* const* d_in, const int* in_sizes, int n_in,
                              void* d_out, int out_size, void* d_ws, size_t ws_size,
                              hipStream_t stream) {
    const float* label = (const float*)d_in[0];
    const float* chh   = (const float*)d_in[1];
    const float* chc   = (const float*)d_in[2];
    const float* W_i   = (const float*)d_in[3];
    const float* b_i   = (const float*)d_in[4];
    const float* W_o   = (const float*)d_in[5];
    const float* b_o   = (const float*)d_in[6];
    const float* W_u   = (const float*)d_in[7];
    const float* b_u   = (const float*)d_in[8];
    const float* W_fl  = (const float*)d_in[9];
    const float* W_fs  = (const float*)d_in[10];
    const float* fbias = (const float*)d_in[11];
    float* out = (float*)d_out;

    char* ws = (char*)d_ws;
    short* xb    = (short*)ws;                          // B x K bf16
    short* Wb    = (short*)(ws + XB_BYTES);             // 2560 x K bf16
    short* gates = (short*)(ws + XB_BYTES + WB_BYTES);  // B x 2560 bf16

    // pack_x: B*288 threads / 256
    pack_x<<<(BROWS * (KDIM / 4)) / 256, 256, 0, stream>>>(label, chh, xb);
    // pack_w: 2560*288 threads / 256
    pack_w<<<(NGATES * (KDIM / 4)) / 256, 256, 0, stream>>>(W_i, W_o, W_u, W_fl, W_fs, Wb);
    // gemm: 128 m-tiles x 20 n-tiles
    dim3 ggrid(BROWS / 128, NGATES / 128);
    gemm_bt<<<ggrid, 256, 0, stream>>>(xb, Wb, gates);
    // epilogue: B*512 threads
    epilogue<<<(BROWS * HDIM) / 256, 256, 0, stream>>>(gates, chc, b_i, b_o, b_u, fbias, out);
}